// Round 18
// baseline (105.735 us; speedup 1.0000x reference)
//
#include <hip/hip_runtime.h>
#include <hip/hip_bf16.h>

#define NSEQ 256
#define DIM 64
#define NB 128
#define NPAIR 384
#define FINF 1e8f
#define LOG2E 1.4426950408889634f
#define LN2 0.6931471805599453f

using f32x4 = __attribute__((ext_vector_type(4))) float;
using s16x8 = __attribute__((ext_vector_type(8))) short;

__device__ __forceinline__ unsigned short bf16u(float f) {
    __hip_bfloat16 h = __float2bfloat16(f);
    return __builtin_bit_cast(unsigned short, h);
}
__device__ __forceinline__ short bf16s(float f) {
    __hip_bfloat16 h = __float2bfloat16(f);
    return __builtin_bit_cast(short, h);
}
__device__ __forceinline__ float min3f(float a, float b, float c) {
    float d; asm("v_min3_f32 %0, %1, %2, %3" : "=v"(d) : "v"(a), "v"(b), "v"(c));
    return d;
}
__device__ __forceinline__ float max3f(float a, float b, float c) {
    float d; asm("v_max3_f32 %0, %1, %2, %3" : "=v"(d) : "v"(a), "v"(b), "v"(c));
    return d;
}

// ---------------------------------------------------------------------------
// Kernel 1: D[p][i][j] = |a_i - b_j|^2, stored ROW-MAJOR S[p][i][j].
// 2 blocks per pair (verified staging/MFMA/sbuf pipeline); NEW writeout:
// straight unswizzle copy — each wave writes 16 full 512B rows, 64 lanes x
// 8B contiguous per instruction -> sector-aligned full-line writes (kills
// the 1.39x RMW write amplification of the old 128B@512B-stride pattern).
// ---------------------------------------------------------------------------
__global__ __launch_bounds__(256, 3)
void dist_kernel(const float* __restrict__ X, const float* __restrict__ Y,
                 unsigned short* __restrict__ S) {
    __shared__ __align__(16) short b_lds[NSEQ * DIM];   // 32 KB; reused as sbuf
    __shared__ __align__(16) short a_lds[128 * DIM];    // 16 KB (this half's A)
    __shared__ float a2[128];
    __shared__ float b2[NSEQ];
    unsigned short* sbuf = reinterpret_cast<unsigned short*>(b_lds);

    const int bid = blockIdx.x;
    const int p = bid >> 1;       // pair 0..383
    const int h = bid & 1;        // row-half 0..1
    const int b = p & (NB - 1);
    const int g = p >> 7;         // 0: (x,y)  1: (x,x)  2: (y,y)
    const float* Arow = (g == 2 ? Y : X) + (size_t)b * NSEQ * DIM
                        + (size_t)h * 128 * DIM;
    const float* Brow = (g == 1 ? X : Y) + (size_t)b * NSEQ * DIM;

    const int t = threadIdx.x;
    {
        const float4* bv = reinterpret_cast<const float4*>(Brow) + t * (DIM / 4);
        float sb = 0.f;
#pragma unroll
        for (int q = 0; q < 8; ++q) {
            float4 b0 = bv[2 * q], b1 = bv[2 * q + 1];
            sb += b0.x * b0.x + b0.y * b0.y + b0.z * b0.z + b0.w * b0.w
                + b1.x * b1.x + b1.y * b1.y + b1.z * b1.z + b1.w * b1.w;
            s16x8 pb = { bf16s(b0.x), bf16s(b0.y), bf16s(b0.z), bf16s(b0.w),
                         bf16s(b1.x), bf16s(b1.y), bf16s(b1.z), bf16s(b1.w) };
            *reinterpret_cast<s16x8*>(&b_lds[t * DIM + ((q ^ (t & 7)) << 3)]) = pb;
        }
        b2[t] = sb;
    }
    if (t < 128) {
        const float4* av = reinterpret_cast<const float4*>(Arow) + t * (DIM / 4);
        float sa = 0.f;
#pragma unroll
        for (int q = 0; q < 8; ++q) {
            float4 a0 = av[2 * q], a1 = av[2 * q + 1];
            sa += a0.x * a0.x + a0.y * a0.y + a0.z * a0.z + a0.w * a0.w
                + a1.x * a1.x + a1.y * a1.y + a1.z * a1.z + a1.w * a1.w;
            s16x8 pa = { bf16s(a0.x), bf16s(a0.y), bf16s(a0.z), bf16s(a0.w),
                         bf16s(a1.x), bf16s(a1.y), bf16s(a1.z), bf16s(a1.w) };
            *reinterpret_cast<s16x8*>(&a_lds[t * DIM + ((q ^ (t & 7)) << 3)]) = pa;
        }
        a2[t] = sa;
    }
    __syncthreads();

    const int wave = t >> 6;
    const int lane = t & 63;
    const int lrow = lane & 15;
    const int lk   = lane >> 4;

    s16x8 bfr[4][2];
    float bn[4];
#pragma unroll
    for (int ct = 0; ct < 4; ++ct) {
        const int c = 64 * wave + ct * 16 + lrow;
#pragma unroll
        for (int kk = 0; kk < 2; ++kk) {
            const int kb = kk * 4 + lk;
            bfr[ct][kk] = *reinterpret_cast<const s16x8*>(
                &b_lds[c * DIM + ((kb ^ (c & 7)) << 3)]);
        }
        bn[ct] = b2[c];
    }
    __syncthreads();  // all waves done with b_lds; it becomes sbuf now

    const size_t pbase = (size_t)p * (NSEQ * NSEQ);
#pragma unroll 1
    for (int sloc = 0; sloc < 2; ++sloc) {
        const int rl0 = sloc * 64;
        const int r0  = h * 128 + rl0;
        s16x8 afr[4][2];
#pragma unroll
        for (int rt = 0; rt < 4; ++rt) {
            const int rl = rl0 + rt * 16 + lrow;
#pragma unroll
            for (int kk = 0; kk < 2; ++kk) {
                const int kb = kk * 4 + lk;
                afr[rt][kk] = *reinterpret_cast<const s16x8*>(
                    &a_lds[rl * DIM + ((kb ^ (rl & 7)) << 3)]);
            }
        }
#pragma unroll
        for (int ct = 0; ct < 4; ++ct) {
            const int c = 64 * wave + ct * 16 + lrow;
#pragma unroll
            for (int rt = 0; rt < 4; ++rt) {
                f32x4 acc = {0.f, 0.f, 0.f, 0.f};
                acc = __builtin_amdgcn_mfma_f32_16x16x32_bf16(afr[rt][0], bfr[ct][0], acc, 0, 0, 0);
                acc = __builtin_amdgcn_mfma_f32_16x16x32_bf16(afr[rt][1], bfr[ct][1], acc, 0, 0, 0);
#pragma unroll
                for (int jv = 0; jv < 4; ++jv) {
                    const int rloc = rt * 16 + lk * 4 + jv;
                    const float dist = a2[rl0 + rloc] + bn[ct] - 2.f * acc[jv];
                    sbuf[rloc * NSEQ + (c ^ (((rloc >> 2) & 3) << 4))] = bf16u(dist);
                }
            }
        }
        __syncthreads();
        // NEW writeout: wave writes rows [16*wave, 16*wave+16) of the stripe,
        // 64 lanes x 8B = one full 512B row per instruction (fully coalesced).
#pragma unroll
        for (int gg = 0; gg < 16; ++gg) {
            const int row = wave * 16 + gg;                 // row within stripe
            const int swz = ((row >> 2) & 3) << 4;
            uint2 v = *reinterpret_cast<const uint2*>(
                &sbuf[row * NSEQ + ((4 * lane) ^ swz)]);
            *reinterpret_cast<uint2*>(
                &S[pbase + (size_t)(r0 + row) * NSEQ + 4 * lane]) = v;
        }
        __syncthreads();
    }
}

// ---------------------------------------------------------------------------
// Kernel 2: soft-DTW DP, self-timed producer/consumer waves (r16/r17-verified
// protocol + cell math, absmax 0.0 x4). NEW: D read row-major DIRECTLY into
// registers — lane L owns row 64w+L; a chunk's 32 D values are 32 consecutive
// ushort loads (2B-aligned always), double-buffered dA/dB so HBM latency
// hides under the ~6000cy chunk chain. No global_load_lds, no vmcnt asm,
// no sdD ring: LDS = boundary slots + flags only (~2KB). OOB j (rails) read
// adjacent rows' positive D or 0xAA guard bytes (tiny negative bf16, exp!=255
// so never NaN) — rail-safe per the r16 analysis.
// ---------------------------------------------------------------------------
__global__ __launch_bounds__(256, 1)
void dtw_kernel(const unsigned short* __restrict__ S, float* __restrict__ rout) {
    __shared__ __align__(16) float bndN[4][3][34];              // 1.6 KB
    __shared__ volatile int prog[4];
    __shared__ volatile int rdprog[4];
    const int t = threadIdx.x;
    const int w = t >> 6;     // wave 0..3
    const int L = t & 63;
    const int p = blockIdx.x;
    const unsigned short* myrow =
        S + (size_t)p * (NSEQ * NSEQ) + (size_t)(64 * w + L) * NSEQ;
    const int cfirst = 2 * w, clast = 2 * w + 9;
    const bool lz = (L == 0);

    if (L == 0) { prog[w] = -1000; rdprog[w] = cfirst - 1; }
    __syncthreads();  // the only block barrier: flag init visible

    auto loadD = [&](unsigned* buf, int c) {  // 32 consecutive ushorts of row
        const unsigned short* src = myrow + (32 * c - 64 * w - L);
#pragma unroll
        for (int u = 0; u < 32; ++u) buf[u] = src[u];
    };

    float s1 = FINF, s2 = FINF, rp = FINF;
    const int finf_bits = __builtin_bit_cast(int, FINF);
    float out_val = 0.f;

    // Softmin cell, base-2 domain, trans-free Schraudolph (verified r14-r17):
    auto stepfn = [&](float dv2, float bt, float btm1) -> float {
        const float bb = lz ? bt : s1;
        const float a  = lz ? btm1 : s2;
        const float m   = min3f(a, bb, rp);
        const float med = __builtin_amdgcn_fmed3f(a, bb, rp);
        const float M   = max3f(a, bb, rp);
        const float x1 = fmaxf(m - med, -126.0f);
        const float x2 = fmaxf(m - M,   -126.0f);
        const float e1 = __builtin_bit_cast(float,
            (int)__builtin_fmaf(x1, 8388608.0f, 1064992212.0f));
        const float e2 = __builtin_bit_cast(float,
            (int)__builtin_fmaf(x2, 8388608.0f, 1064992212.0f));
        const float e = 1.0f + (e1 + e2);
        const float lg = __builtin_fmaf((float)__builtin_bit_cast(int, e),
                                        1.1920929e-7f, -126.94269504f);
        const float rn = (m - lg) + dv2;
        s2 = s1;
        s1 = __builtin_bit_cast(float,
            __builtin_amdgcn_update_dpp(finf_bits, __builtin_bit_cast(int, rn),
                                        0x138 /*wave_shr:1*/, 0xF, 0xF, false));
        rp = rn;
        return rn;
    };

    auto polls = [&](int c) {
        if (w < 3) {
            while (rdprog[w + 1] < c - 2) __builtin_amdgcn_s_sleep(2);
        }
        if (w > 0 && c <= 2 * w + 7) {
            while (prog[w - 1] < c) __builtin_amdgcn_s_sleep(2);
        }
        asm volatile("" ::: "memory");
    };

    auto process = [&](int c, const unsigned* dbuf) {
        // --- boundary from wave w-1 ---
        float bwf[32], carA, carB;
        if (w == 0) {
#pragma unroll
            for (int u = 0; u < 32; ++u) bwf[u] = FINF;
            carA = FINF;
            carB = (c == 0) ? 0.f : FINF;  // R[-1][-1] = 0 at very start
        } else {
            const float* bs = &bndN[w][c % 3][0];
            carB = bs[0];
            carA = bs[1];
#pragma unroll
            for (int u = 0; u < 32; ++u) bwf[u] = bs[2 + u];
        }
        // --- 32 steps ---
        float rb[32];
        rb[0] = stepfn(__builtin_bit_cast(float, dbuf[0] << 16) * LOG2E,
                       carA, carB);
        rb[1] = stepfn(__builtin_bit_cast(float, dbuf[1] << 16) * LOG2E,
                       bwf[0], carA);
#pragma unroll
        for (int u = 2; u < 32; ++u)
            rb[u] = stepfn(__builtin_bit_cast(float, dbuf[u] << 16) * LOG2E,
                           bwf[u - 1], bwf[u - 2]);

        // --- publish boundary for wave w+1, then flag ---
        if (w < 3) {
            if (L == 63) {
                float* bd = &bndN[w + 1][c % 3][0];
#pragma unroll
                for (int u = 0; u < 32; ++u) bd[2 + u] = rb[u];
                float* bd2 = &bndN[w + 1][(c + 1) % 3][0];
                bd2[0] = rb[30];  // carB for reader chunk c+1
                bd2[1] = rb[31];  // carA for reader chunk c+1
            }
            asm volatile("s_waitcnt lgkmcnt(0)" ::: "memory");
            if (L == 63) prog[w] = c;
        } else if (c == 15 && L == 63) {
            out_val = rb[30];  // step 510 = R[255][255]
        }
        asm volatile("" ::: "memory");
        if (w > 0 && L == 0) rdprog[w] = c;  // release writer's ring
    };

    unsigned dA[32], dB[32];
    loadD(dA, cfirst);

#pragma unroll 1
    for (int cb = cfirst; cb <= clast; cb += 2) {  // 5 iterations of 2 chunks
        polls(cb);
        loadD(dB, cb + 1);            // cb+1 <= clast always (10 even chunks)
        process(cb, dA);
        polls(cb + 1);
        if (cb + 2 <= clast) loadD(dA, cb + 2);
        process(cb + 1, dB);
    }

    if (w == 3 && L == 63) rout[p] = out_val * LN2;  // base-2 -> nats
}

// ---------------------------------------------------------------------------
// Kernel 3: loss = mean_b( r[b] - 0.5*(r[b+128] + r[b+256]) ) + 1e-5
// ---------------------------------------------------------------------------
__global__ void reduce_kernel(const float* __restrict__ rr, float* __restrict__ out) {
    const int t = threadIdx.x;  // 128 threads
    float v = rr[t] - 0.5f * (rr[t + 128] + rr[t + 256]);
#pragma unroll
    for (int o = 32; o > 0; o >>= 1) v += __shfl_down(v, o);
    __shared__ float sred[2];
    if ((t & 63) == 0) sred[t >> 6] = v;
    __syncthreads();
    if (t == 0) out[0] = (sred[0] + sred[1]) * (1.f / 128.f) + 1e-5f;
}

extern "C" void kernel_launch(void* const* d_in, const int* in_sizes, int n_in,
                              void* d_out, int out_size, void* d_ws, size_t ws_size,
                              hipStream_t stream) {
    const float* X = (const float*)d_in[0];  // outputs (128,256,64) f32
    const float* Y = (const float*)d_in[1];  // targets (128,256,64) f32
    float* out = (float*)d_out;

    const size_t dbytes = (size_t)NPAIR * NSEQ * NSEQ * sizeof(unsigned short);
    // 128B guard on each side of S (rail reads spill up to +-126B), + rws
    const size_t need = 128 + dbytes + 128 + (size_t)NPAIR * sizeof(float);
    if (ws_size < need) {
        hipMemsetAsync(d_out, 0x7f, sizeof(float), stream);  // sentinel
        return;
    }
    unsigned short* Sws = (unsigned short*)d_ws + 64;  // front guard
    float* rws = (float*)((char*)d_ws + 128 + dbytes + 128);

    dist_kernel<<<2 * NPAIR, 256, 0, stream>>>(X, Y, Sws);
    dtw_kernel<<<NPAIR, 256, 0, stream>>>(Sws, rws);
    reduce_kernel<<<1, 128, 0, stream>>>(rws, out);
}

// Round 19
// 92.926 us; speedup vs baseline: 1.1378x; 1.1378x over previous
//
#include <hip/hip_runtime.h>
#include <hip/hip_bf16.h>

#define NSEQ 256
#define DIM 64
#define NB 128
#define NPAIR 384
#define FINF 1e8f
#define LOG2E 1.4426950408889634f
#define LN2 0.6931471805599453f

using f32x4 = __attribute__((ext_vector_type(4))) float;
using f32x2 = __attribute__((ext_vector_type(2))) float;
using s16x8 = __attribute__((ext_vector_type(8))) short;

__device__ __forceinline__ unsigned short bf16u(float f) {
    __hip_bfloat16 h = __float2bfloat16(f);
    return __builtin_bit_cast(unsigned short, h);
}
__device__ __forceinline__ short bf16s(float f) {
    __hip_bfloat16 h = __float2bfloat16(f);
    return __builtin_bit_cast(short, h);
}
__device__ __forceinline__ float min3f(float a, float b, float c) {
    float d; asm("v_min3_f32 %0, %1, %2, %3" : "=v"(d) : "v"(a), "v"(b), "v"(c));
    return d;
}
__device__ __forceinline__ float max3f(float a, float b, float c) {
    float d; asm("v_max3_f32 %0, %1, %2, %3" : "=v"(d) : "v"(a), "v"(b), "v"(c));
    return d;
}

// ---------------------------------------------------------------------------
// Kernel 1: D[p][i][j] = |a_i - b_j|^2, stored DIAGONAL-MAJOR:
//   S[p][(i+j) & 255][i]. 2 blocks per pair. (r17 verbatim — verified)
// ---------------------------------------------------------------------------
__global__ __launch_bounds__(256, 3)
void dist_kernel(const float* __restrict__ X, const float* __restrict__ Y,
                 unsigned short* __restrict__ S) {
    __shared__ __align__(16) short b_lds[NSEQ * DIM];   // 32 KB; reused as sbuf
    __shared__ __align__(16) short a_lds[128 * DIM];    // 16 KB (this half's A)
    __shared__ float a2[128];
    __shared__ float b2[NSEQ];
    unsigned short* sbuf = reinterpret_cast<unsigned short*>(b_lds);

    const int bid = blockIdx.x;
    const int p = bid >> 1;       // pair 0..383
    const int h = bid & 1;        // row-half 0..1
    const int b = p & (NB - 1);
    const int g = p >> 7;         // 0: (x,y)  1: (x,x)  2: (y,y)
    const float* Arow = (g == 2 ? Y : X) + (size_t)b * NSEQ * DIM
                        + (size_t)h * 128 * DIM;
    const float* Brow = (g == 1 ? X : Y) + (size_t)b * NSEQ * DIM;

    const int t = threadIdx.x;
    {
        const float4* bv = reinterpret_cast<const float4*>(Brow) + t * (DIM / 4);
        float sb = 0.f;
#pragma unroll
        for (int q = 0; q < 8; ++q) {
            float4 b0 = bv[2 * q], b1 = bv[2 * q + 1];
            sb += b0.x * b0.x + b0.y * b0.y + b0.z * b0.z + b0.w * b0.w
                + b1.x * b1.x + b1.y * b1.y + b1.z * b1.z + b1.w * b1.w;
            s16x8 pb = { bf16s(b0.x), bf16s(b0.y), bf16s(b0.z), bf16s(b0.w),
                         bf16s(b1.x), bf16s(b1.y), bf16s(b1.z), bf16s(b1.w) };
            *reinterpret_cast<s16x8*>(&b_lds[t * DIM + ((q ^ (t & 7)) << 3)]) = pb;
        }
        b2[t] = sb;
    }
    if (t < 128) {
        const float4* av = reinterpret_cast<const float4*>(Arow) + t * (DIM / 4);
        float sa = 0.f;
#pragma unroll
        for (int q = 0; q < 8; ++q) {
            float4 a0 = av[2 * q], a1 = av[2 * q + 1];
            sa += a0.x * a0.x + a0.y * a0.y + a0.z * a0.z + a0.w * a0.w
                + a1.x * a1.x + a1.y * a1.y + a1.z * a1.z + a1.w * a1.w;
            s16x8 pa = { bf16s(a0.x), bf16s(a0.y), bf16s(a0.z), bf16s(a0.w),
                         bf16s(a1.x), bf16s(a1.y), bf16s(a1.z), bf16s(a1.w) };
            *reinterpret_cast<s16x8*>(&a_lds[t * DIM + ((q ^ (t & 7)) << 3)]) = pa;
        }
        a2[t] = sa;
    }
    __syncthreads();

    const int wave = t >> 6;
    const int lane = t & 63;
    const int lrow = lane & 15;
    const int lk   = lane >> 4;

    s16x8 bfr[4][2];
    float bn[4];
#pragma unroll
    for (int ct = 0; ct < 4; ++ct) {
        const int c = 64 * wave + ct * 16 + lrow;
#pragma unroll
        for (int kk = 0; kk < 2; ++kk) {
            const int kb = kk * 4 + lk;
            bfr[ct][kk] = *reinterpret_cast<const s16x8*>(
                &b_lds[c * DIM + ((kb ^ (c & 7)) << 3)]);
        }
        bn[ct] = b2[c];
    }
    __syncthreads();  // all waves done with b_lds; it becomes sbuf now

    const size_t pbase = (size_t)p * (NSEQ * NSEQ);
#pragma unroll 1
    for (int sloc = 0; sloc < 2; ++sloc) {
        const int rl0 = sloc * 64;
        const int r0  = h * 128 + rl0;
        s16x8 afr[4][2];
#pragma unroll
        for (int rt = 0; rt < 4; ++rt) {
            const int rl = rl0 + rt * 16 + lrow;
#pragma unroll
            for (int kk = 0; kk < 2; ++kk) {
                const int kb = kk * 4 + lk;
                afr[rt][kk] = *reinterpret_cast<const s16x8*>(
                    &a_lds[rl * DIM + ((kb ^ (rl & 7)) << 3)]);
            }
        }
#pragma unroll
        for (int ct = 0; ct < 4; ++ct) {
            const int c = 64 * wave + ct * 16 + lrow;
#pragma unroll
            for (int rt = 0; rt < 4; ++rt) {
                f32x4 acc = {0.f, 0.f, 0.f, 0.f};
                acc = __builtin_amdgcn_mfma_f32_16x16x32_bf16(afr[rt][0], bfr[ct][0], acc, 0, 0, 0);
                acc = __builtin_amdgcn_mfma_f32_16x16x32_bf16(afr[rt][1], bfr[ct][1], acc, 0, 0, 0);
#pragma unroll
                for (int jv = 0; jv < 4; ++jv) {
                    const int rloc = rt * 16 + lk * 4 + jv;
                    const float dist = a2[rl0 + rloc] + bn[ct] - 2.f * acc[jv];
                    sbuf[rloc * NSEQ + (c ^ (((rloc >> 2) & 3) << 4))] = bf16u(dist);
                }
            }
        }
        __syncthreads();
        const int sl = lane >> 4;
        const int q  = lane & 15;
#pragma unroll
        for (int gg = 0; gg < 16; ++gg) {
            const int s = 64 * wave + gg * 4 + sl;
            const int il0 = 4 * q;
            const int swz = ((q & 3) << 4);
            const int j0 = (s - (r0 + il0 + 0)) & 255;
            const int j1 = (s - (r0 + il0 + 1)) & 255;
            const int j2 = (s - (r0 + il0 + 2)) & 255;
            const int j3 = (s - (r0 + il0 + 3)) & 255;
            unsigned int e0 = sbuf[(il0 + 0) * NSEQ + (j0 ^ swz)];
            unsigned int e1 = sbuf[(il0 + 1) * NSEQ + (j1 ^ swz)];
            unsigned int e2 = sbuf[(il0 + 2) * NSEQ + (j2 ^ swz)];
            unsigned int e3 = sbuf[(il0 + 3) * NSEQ + (j3 ^ swz)];
            uint2 w;
            w.x = e0 | (e1 << 16);
            w.y = e2 | (e3 << 16);
            *reinterpret_cast<uint2*>(&S[pbase + (size_t)s * NSEQ + r0 + 4 * q]) = w;
        }
        __syncthreads();
    }
}

// ---------------------------------------------------------------------------
// Kernel 2: soft-DTW DP, self-timed producer/consumer waves — r17 protocol,
// staging, vmcnt and cell math VERBATIM (absmax 0.0 x4). Two changes, both
// pure LDS-op reductions (the CU-shared LDS pipe is the measured bottleneck):
//  (a) handoff slots stride 36 floats, read/written as b128/b64 vectors
//      (34 scalar reads -> 9 vec; 36 scalar writes -> 10 vec)
//  (b) dvv via pair-share: instr i lane L reads ONE b32 = cols {2*(L/2),+1}
//      of diag 2i+(L&1); DPP quad-swap (0xB1) + half-selects give each lane
//      its own column of both diags: 32 scalar reads -> 16 b32 + ~11 VALU.
// ---------------------------------------------------------------------------
__global__ __launch_bounds__(256, 2)
void dtw_kernel(const unsigned short* __restrict__ S, float* __restrict__ rout) {
    __shared__ __align__(16) unsigned short sdD[4 * 3 * 2048];  // 48 KB
    __shared__ __align__(16) float bndN[4][3][36];              // 1.7 KB
    __shared__ volatile int prog[4];
    __shared__ volatile int rdprog[4];
    const int t = threadIdx.x;
    const int w = t >> 6;     // wave 0..3
    const int L = t & 63;
    const int p = blockIdx.x;
    const unsigned short* Sp = S + (size_t)p * (NSEQ * NSEQ);
    const int cfirst = 2 * w, clast = 2 * w + 9;
    const int lrow = L >> 3, lcol = L & 7;
    const bool lz = (L == 0);

    if (L == 0) { prog[w] = -1000; rdprog[w] = cfirst - 1; }
    __syncthreads();  // the only block barrier: flag init visible

    auto stageck = [&](int cc) {  // 32 rows x 128B slice -> slot cc%3 (4 loads)
        const int slot = cc % 3;
#pragma unroll
        for (int k = 0; k < 4; ++k) {
            const int row = (32 * cc + 8 * k + lrow) & 255;
            const char* src = (const char*)Sp + row * 512 + w * 128 + lcol * 16;
            __builtin_amdgcn_global_load_lds(
                (const __attribute__((address_space(1))) void*)src,
                (__attribute__((address_space(3))) void*)
                    &sdD[w * 6144 + slot * 2048 + k * 512],
                16, 0, 0);
        }
    };

    stageck(cfirst); stageck(cfirst + 1);

    float s1 = FINF, s2 = FINF, rp = FINF;
    const int finf_bits = __builtin_bit_cast(int, FINF);
    float out_val = 0.f;

    // Softmin cell, base-2 domain, trans-free Schraudolph (verified r14-r17):
    auto stepfn = [&](float dv2, float bt, float btm1) -> float {
        const float bb = lz ? bt : s1;
        const float a  = lz ? btm1 : s2;
        const float m   = min3f(a, bb, rp);
        const float med = __builtin_amdgcn_fmed3f(a, bb, rp);
        const float M   = max3f(a, bb, rp);
        const float x1 = fmaxf(m - med, -126.0f);
        const float x2 = fmaxf(m - M,   -126.0f);
        const float e1 = __builtin_bit_cast(float,
            (int)__builtin_fmaf(x1, 8388608.0f, 1064992212.0f));
        const float e2 = __builtin_bit_cast(float,
            (int)__builtin_fmaf(x2, 8388608.0f, 1064992212.0f));
        const float e = 1.0f + (e1 + e2);
        const float lg = __builtin_fmaf((float)__builtin_bit_cast(int, e),
                                        1.1920929e-7f, -126.94269504f);
        const float rn = (m - lg) + dv2;
        s2 = s1;
        s1 = __builtin_bit_cast(float,
            __builtin_amdgcn_update_dpp(finf_bits, __builtin_bit_cast(int, rn),
                                        0x138 /*wave_shr:1*/, 0xF, 0xF, false));
        rp = rn;
        return rn;
    };

    const bool odd = (L & 1);
    const int dvoff_b = ((L & 1) * 64 + 2 * (L >> 1)) * 2;  // byte offset

#pragma unroll 1
    for (int c = cfirst; c <= clast; ++c) {
        // back-pressure: don't outrun our reader's ring-3
        if (w < 3) {
            while (rdprog[w + 1] < c - 2) __builtin_amdgcn_s_sleep(2);
        }
        // boundary availability (writer's real chunks end at 2w+7)
        if (w > 0 && c <= 2 * w + 7) {
            while (prog[w - 1] < c) __builtin_amdgcn_s_sleep(2);
        }
        asm volatile("" ::: "memory");
        // chunk c staged? counted wait (ring 3, prefetch 2)
        if (c < clast) asm volatile("s_waitcnt vmcnt(4)" ::: "memory");
        else           asm volatile("s_waitcnt vmcnt(0)" ::: "memory");

        // --- dvv pair-share: 16 b32 reads + DPP swap + half-selects ---
        float dvv[32];
        {
            const char* sb = (const char*)&sdD[w * 6144 + (c % 3) * 2048]
                             + dvoff_b;
#pragma unroll
            for (int i = 0; i < 16; ++i) {
                const unsigned own = *reinterpret_cast<const unsigned*>(
                    sb + i * 256);
                const unsigned nb = (unsigned)__builtin_amdgcn_update_dpp(
                    0, (int)own, 0xB1 /*quad_perm 1,0,3,2*/, 0xF, 0xF, true);
                const unsigned uA = odd ? (nb >> 16) : (own & 0xffffu);
                const unsigned uB = odd ? (own >> 16) : (nb & 0xffffu);
                dvv[2 * i]     = __builtin_bit_cast(float, uA << 16) * LOG2E;
                dvv[2 * i + 1] = __builtin_bit_cast(float, uB << 16) * LOG2E;
            }
        }
        // --- boundary from wave w-1 (vectorized reads) ---
        float bwf[32], carA, carB;
        if (w == 0) {
#pragma unroll
            for (int u = 0; u < 32; ++u) bwf[u] = FINF;
            carA = FINF;
            carB = (c == 0) ? 0.f : FINF;  // R[-1][-1] = 0 at very start
        } else {
            const float* bs = &bndN[w][c % 3][0];
            f32x4 q[8];
#pragma unroll
            for (int i = 0; i < 8; ++i)
                q[i] = *reinterpret_cast<const f32x4*>(bs + 4 * i);
            const f32x2 qt = *reinterpret_cast<const f32x2*>(bs + 32);
            carB = q[0][0];
            carA = q[0][1];
#pragma unroll
            for (int u = 0; u < 30; ++u) bwf[u] = q[(u + 2) >> 2][(u + 2) & 3];
            bwf[30] = qt[0];
            bwf[31] = qt[1];
        }
        // --- prefetch next chunk (private slot, consumed 2 iters ago) ---
        if (c + 2 <= clast) stageck(c + 2);

        // --- 32 steps ---
        float rb[32];
        rb[0] = stepfn(dvv[0], carA, carB);
        rb[1] = stepfn(dvv[1], bwf[0], carA);
#pragma unroll
        for (int u = 2; u < 32; ++u)
            rb[u] = stepfn(dvv[u], bwf[u - 1], bwf[u - 2]);

        // --- publish boundary for wave w+1 (vectorized), then flag ---
        if (w < 3) {
            if (L == 63) {
                float* bd = &bndN[w + 1][c % 3][0];
                *reinterpret_cast<f32x2*>(bd + 2) = f32x2{rb[0], rb[1]};
#pragma unroll
                for (int i = 0; i < 7; ++i)
                    *reinterpret_cast<f32x4*>(bd + 4 + 4 * i) =
                        f32x4{rb[2 + 4 * i], rb[3 + 4 * i],
                              rb[4 + 4 * i], rb[5 + 4 * i]};
                *reinterpret_cast<f32x2*>(bd + 32) = f32x2{rb[30], rb[31]};
                float* bd2 = &bndN[w + 1][(c + 1) % 3][0];
                *reinterpret_cast<f32x2*>(bd2) = f32x2{rb[30], rb[31]};
            }
            asm volatile("s_waitcnt lgkmcnt(0)" ::: "memory");
            if (L == 63) prog[w] = c;
        } else if (c == 15 && L == 63) {
            out_val = rb[30];  // step 510 = R[255][255]
        }
        asm volatile("" ::: "memory");
        if (w > 0 && L == 0) rdprog[w] = c;  // release writer's ring
    }

    if (w == 3 && L == 63) rout[p] = out_val * LN2;  // base-2 -> nats
}

// ---------------------------------------------------------------------------
// Kernel 3: loss = mean_b( r[b] - 0.5*(r[b+128] + r[b+256]) ) + 1e-5
// ---------------------------------------------------------------------------
__global__ void reduce_kernel(const float* __restrict__ rr, float* __restrict__ out) {
    const int t = threadIdx.x;  // 128 threads
    float v = rr[t] - 0.5f * (rr[t + 128] + rr[t + 256]);
#pragma unroll
    for (int o = 32; o > 0; o >>= 1) v += __shfl_down(v, o);
    __shared__ float sred[2];
    if ((t & 63) == 0) sred[t >> 6] = v;
    __syncthreads();
    if (t == 0) out[0] = (sred[0] + sred[1]) * (1.f / 128.f) + 1e-5f;
}

extern "C" void kernel_launch(void* const* d_in, const int* in_sizes, int n_in,
                              void* d_out, int out_size, void* d_ws, size_t ws_size,
                              hipStream_t stream) {
    const float* X = (const float*)d_in[0];  // outputs (128,256,64) f32
    const float* Y = (const float*)d_in[1];  // targets (128,256,64) f32
    float* out = (float*)d_out;

    const size_t dbytes = (size_t)NPAIR * NSEQ * NSEQ * sizeof(unsigned short);
    const size_t need = dbytes + (size_t)NPAIR * sizeof(float);
    if (ws_size < need) {
        hipMemsetAsync(d_out, 0x7f, sizeof(float), stream);  // sentinel
        return;
    }
    unsigned short* Sws = (unsigned short*)d_ws;
    float* rws = (float*)((char*)d_ws + dbytes);

    dist_kernel<<<2 * NPAIR, 256, 0, stream>>>(X, Y, Sws);
    dtw_kernel<<<NPAIR, 256, 0, stream>>>(Sws, rws);
    reduce_kernel<<<1, 128, 0, stream>>>(rws, out);
}

// Round 20
// 81.125 us; speedup vs baseline: 1.3034x; 1.1455x over previous
//
#include <hip/hip_runtime.h>
#include <hip/hip_bf16.h>

#define NSEQ 256
#define DIM 64
#define NB 128
#define NPAIR 384
#define FINF 1e8f
#define LOG2E 1.4426950408889634f
#define LN2 0.6931471805599453f

using f32x4 = __attribute__((ext_vector_type(4))) float;
using s16x8 = __attribute__((ext_vector_type(8))) short;

__device__ __forceinline__ unsigned short bf16u(float f) {
    __hip_bfloat16 h = __float2bfloat16(f);
    return __builtin_bit_cast(unsigned short, h);
}
__device__ __forceinline__ short bf16s(float f) {
    __hip_bfloat16 h = __float2bfloat16(f);
    return __builtin_bit_cast(short, h);
}
__device__ __forceinline__ float min3f(float a, float b, float c) {
    float d; asm("v_min3_f32 %0, %1, %2, %3" : "=v"(d) : "v"(a), "v"(b), "v"(c));
    return d;
}
__device__ __forceinline__ float max3f(float a, float b, float c) {
    float d; asm("v_max3_f32 %0, %1, %2, %3" : "=v"(d) : "v"(a), "v"(b), "v"(c));
    return d;
}

// ---------------------------------------------------------------------------
// Kernel 1: D[p][i][j] = |a_i - b_j|^2, stored DIAGONAL-MAJOR:
//   S[p][(i+j) & 255][i]. ONE block per pair (r7/r8-verified version —
//   B staged once, 66KB LDS, 2 blocks/CU; the r9 2-block split restaged B
//   twice and measured ~7us slower).
// ---------------------------------------------------------------------------
__global__ __launch_bounds__(256, 2)
void dist_kernel(const float* __restrict__ X, const float* __restrict__ Y,
                 unsigned short* __restrict__ S) {
    __shared__ __align__(16) short a_lds[NSEQ * DIM];
    __shared__ __align__(16) short b_lds[NSEQ * DIM];  // reused as sbuf later
    __shared__ float a2[NSEQ];
    __shared__ float b2[NSEQ];
    unsigned short* sbuf = reinterpret_cast<unsigned short*>(b_lds);

    const int p = blockIdx.x;
    const int b = p & (NB - 1);
    const int g = p >> 7;  // 0: (x,y)  1: (x,x)  2: (y,y)
    const float* Arow = (g == 2 ? Y : X) + (size_t)b * NSEQ * DIM;
    const float* Brow = (g == 1 ? X : Y) + (size_t)b * NSEQ * DIM;

    const int t = threadIdx.x;
    {
        const float4* av = reinterpret_cast<const float4*>(Arow) + t * (DIM / 4);
        const float4* bv = reinterpret_cast<const float4*>(Brow) + t * (DIM / 4);
        float sa = 0.f, sb = 0.f;
#pragma unroll
        for (int q = 0; q < 8; ++q) {
            float4 a0 = av[2 * q], a1 = av[2 * q + 1];
            float4 b0 = bv[2 * q], b1 = bv[2 * q + 1];
            sa += a0.x * a0.x + a0.y * a0.y + a0.z * a0.z + a0.w * a0.w
                + a1.x * a1.x + a1.y * a1.y + a1.z * a1.z + a1.w * a1.w;
            sb += b0.x * b0.x + b0.y * b0.y + b0.z * b0.z + b0.w * b0.w
                + b1.x * b1.x + b1.y * b1.y + b1.z * b1.z + b1.w * b1.w;
            s16x8 pa = { bf16s(a0.x), bf16s(a0.y), bf16s(a0.z), bf16s(a0.w),
                         bf16s(a1.x), bf16s(a1.y), bf16s(a1.z), bf16s(a1.w) };
            s16x8 pb = { bf16s(b0.x), bf16s(b0.y), bf16s(b0.z), bf16s(b0.w),
                         bf16s(b1.x), bf16s(b1.y), bf16s(b1.z), bf16s(b1.w) };
            const int off = t * DIM + ((q ^ (t & 7)) << 3);
            *reinterpret_cast<s16x8*>(&a_lds[off]) = pa;
            *reinterpret_cast<s16x8*>(&b_lds[off]) = pb;
        }
        a2[t] = sa;
        b2[t] = sb;
    }
    __syncthreads();

    const int wave = t >> 6;
    const int lane = t & 63;
    const int lrow = lane & 15;
    const int lk   = lane >> 4;

    s16x8 bfr[4][2];
    float bn[4];
#pragma unroll
    for (int ct = 0; ct < 4; ++ct) {
        const int c = 64 * wave + ct * 16 + lrow;
#pragma unroll
        for (int kk = 0; kk < 2; ++kk) {
            const int kb = kk * 4 + lk;
            bfr[ct][kk] = *reinterpret_cast<const s16x8*>(
                &b_lds[c * DIM + ((kb ^ (c & 7)) << 3)]);
        }
        bn[ct] = b2[c];
    }
    __syncthreads();  // all waves done with b_lds; it becomes sbuf now

    const size_t pbase = (size_t)p * (NSEQ * NSEQ);
#pragma unroll 1
    for (int stripe = 0; stripe < 4; ++stripe) {
        const int r0 = stripe * 64;
        s16x8 afr[4][2];
#pragma unroll
        for (int rt = 0; rt < 4; ++rt) {
            const int r = r0 + rt * 16 + lrow;
#pragma unroll
            for (int kk = 0; kk < 2; ++kk) {
                const int kb = kk * 4 + lk;
                afr[rt][kk] = *reinterpret_cast<const s16x8*>(
                    &a_lds[r * DIM + ((kb ^ (r & 7)) << 3)]);
            }
        }
#pragma unroll
        for (int ct = 0; ct < 4; ++ct) {
            const int c = 64 * wave + ct * 16 + lrow;
#pragma unroll
            for (int rt = 0; rt < 4; ++rt) {
                f32x4 acc = {0.f, 0.f, 0.f, 0.f};
                acc = __builtin_amdgcn_mfma_f32_16x16x32_bf16(afr[rt][0], bfr[ct][0], acc, 0, 0, 0);
                acc = __builtin_amdgcn_mfma_f32_16x16x32_bf16(afr[rt][1], bfr[ct][1], acc, 0, 0, 0);
#pragma unroll
                for (int jv = 0; jv < 4; ++jv) {
                    const int rloc = rt * 16 + lk * 4 + jv;
                    const float dist = a2[r0 + rloc] + bn[ct] - 2.f * acc[jv];
                    sbuf[rloc * NSEQ + (c ^ (((rloc >> 2) & 3) << 4))] = bf16u(dist);
                }
            }
        }
        __syncthreads();
        const int sl = lane >> 4;
        const int q  = lane & 15;
#pragma unroll
        for (int gg = 0; gg < 16; ++gg) {
            const int s = 64 * wave + gg * 4 + sl;
            const int il0 = 4 * q;
            const int swz = ((q & 3) << 4);
            const int j0 = (s - (r0 + il0 + 0)) & 255;
            const int j1 = (s - (r0 + il0 + 1)) & 255;
            const int j2 = (s - (r0 + il0 + 2)) & 255;
            const int j3 = (s - (r0 + il0 + 3)) & 255;
            unsigned int e0 = sbuf[(il0 + 0) * NSEQ + (j0 ^ swz)];
            unsigned int e1 = sbuf[(il0 + 1) * NSEQ + (j1 ^ swz)];
            unsigned int e2 = sbuf[(il0 + 2) * NSEQ + (j2 ^ swz)];
            unsigned int e3 = sbuf[(il0 + 3) * NSEQ + (j3 ^ swz)];
            uint2 w;
            w.x = e0 | (e1 << 16);
            w.y = e2 | (e3 << 16);
            *reinterpret_cast<uint2*>(&S[pbase + (size_t)s * NSEQ + r0 + 4 * q]) = w;
        }
        __syncthreads();
    }
}

// ---------------------------------------------------------------------------
// Kernel 2: soft-DTW DP, self-timed producer/consumer waves — r17 VERBATIM
// (best measured: 50.3us, absmax 0.0). Wave w owns rows [64w,64w+64),
// chunks c in [2w, 2w+9] of 32 diagonals; flag protocol + ring-3 staging
// via global_load_lds, counted vmcnt; trans-free Schraudolph softmin.
// ---------------------------------------------------------------------------
__global__ __launch_bounds__(256, 2)
void dtw_kernel(const unsigned short* __restrict__ S, float* __restrict__ rout) {
    __shared__ __align__(16) unsigned short sdD[4 * 3 * 2048];  // 48 KB
    __shared__ __align__(16) float bndN[4][3][34];              // 1.6 KB
    __shared__ volatile int prog[4];
    __shared__ volatile int rdprog[4];
    const int t = threadIdx.x;
    const int w = t >> 6;     // wave 0..3
    const int L = t & 63;
    const int p = blockIdx.x;
    const unsigned short* Sp = S + (size_t)p * (NSEQ * NSEQ);
    const int cfirst = 2 * w, clast = 2 * w + 9;
    const int lrow = L >> 3, lcol = L & 7;
    const bool lz = (L == 0);

    if (L == 0) { prog[w] = -1000; rdprog[w] = cfirst - 1; }
    __syncthreads();  // the only block barrier: flag init visible

    auto stageck = [&](int cc) {  // 32 rows x 128B slice -> slot cc%3 (4 loads)
        const int slot = cc % 3;
#pragma unroll
        for (int k = 0; k < 4; ++k) {
            const int row = (32 * cc + 8 * k + lrow) & 255;
            const char* src = (const char*)Sp + row * 512 + w * 128 + lcol * 16;
            __builtin_amdgcn_global_load_lds(
                (const __attribute__((address_space(1))) void*)src,
                (__attribute__((address_space(3))) void*)
                    &sdD[w * 6144 + slot * 2048 + k * 512],
                16, 0, 0);
        }
    };

    stageck(cfirst); stageck(cfirst + 1);

    float s1 = FINF, s2 = FINF, rp = FINF;
    const int finf_bits = __builtin_bit_cast(int, FINF);
    float out_val = 0.f;

    // Softmin cell, base-2 domain, trans-free Schraudolph (verified r14-r17):
    auto stepfn = [&](float dv2, float bt, float btm1) -> float {
        const float bb = lz ? bt : s1;
        const float a  = lz ? btm1 : s2;
        const float m   = min3f(a, bb, rp);
        const float med = __builtin_amdgcn_fmed3f(a, bb, rp);
        const float M   = max3f(a, bb, rp);
        const float x1 = fmaxf(m - med, -126.0f);
        const float x2 = fmaxf(m - M,   -126.0f);
        const float e1 = __builtin_bit_cast(float,
            (int)__builtin_fmaf(x1, 8388608.0f, 1064992212.0f));
        const float e2 = __builtin_bit_cast(float,
            (int)__builtin_fmaf(x2, 8388608.0f, 1064992212.0f));
        const float e = 1.0f + (e1 + e2);
        const float lg = __builtin_fmaf((float)__builtin_bit_cast(int, e),
                                        1.1920929e-7f, -126.94269504f);
        const float rn = (m - lg) + dv2;
        s2 = s1;
        s1 = __builtin_bit_cast(float,
            __builtin_amdgcn_update_dpp(finf_bits, __builtin_bit_cast(int, rn),
                                        0x138 /*wave_shr:1*/, 0xF, 0xF, false));
        rp = rn;
        return rn;
    };

#pragma unroll 1
    for (int c = cfirst; c <= clast; ++c) {
        // back-pressure: don't outrun our reader's ring-3
        if (w < 3) {
            while (rdprog[w + 1] < c - 2) __builtin_amdgcn_s_sleep(2);
        }
        // boundary availability (writer's real chunks end at 2w+7)
        if (w > 0 && c <= 2 * w + 7) {
            while (prog[w - 1] < c) __builtin_amdgcn_s_sleep(2);
        }
        asm volatile("" ::: "memory");
        // chunk c staged? counted wait (ring 3, prefetch 2)
        if (c < clast) asm volatile("s_waitcnt vmcnt(4)" ::: "memory");
        else           asm volatile("s_waitcnt vmcnt(0)" ::: "memory");

        // --- D*log2e for this chunk: row u at short-offset u*64, lane L ---
        float dvv[32];
        {
            const unsigned short* db = &sdD[w * 6144 + (c % 3) * 2048 + L];
#pragma unroll
            for (int u = 0; u < 32; ++u)
                dvv[u] = __builtin_bit_cast(float,
                             (unsigned)db[u * 64] << 16) * LOG2E;
        }
        // --- boundary from wave w-1 ---
        float bwf[32], carA, carB;
        if (w == 0) {
#pragma unroll
            for (int u = 0; u < 32; ++u) bwf[u] = FINF;
            carA = FINF;
            carB = (c == 0) ? 0.f : FINF;  // R[-1][-1] = 0 at very start
        } else {
            const float* bs = &bndN[w][c % 3][0];
            carB = bs[0];
            carA = bs[1];
#pragma unroll
            for (int u = 0; u < 32; ++u) bwf[u] = bs[2 + u];
        }
        // --- prefetch next chunk (private slot, consumed 2 iters ago) ---
        if (c + 2 <= clast) stageck(c + 2);

        // --- 32 steps ---
        float rb[32];
        rb[0] = stepfn(dvv[0], carA, carB);
        rb[1] = stepfn(dvv[1], bwf[0], carA);
#pragma unroll
        for (int u = 2; u < 32; ++u)
            rb[u] = stepfn(dvv[u], bwf[u - 1], bwf[u - 2]);

        // --- publish boundary for wave w+1, then flag ---
        if (w < 3) {
            if (L == 63) {
                float* bd = &bndN[w + 1][c % 3][0];
#pragma unroll
                for (int u = 0; u < 32; ++u) bd[2 + u] = rb[u];
                float* bd2 = &bndN[w + 1][(c + 1) % 3][0];
                bd2[0] = rb[30];  // carB for reader chunk c+1
                bd2[1] = rb[31];  // carA for reader chunk c+1
            }
            asm volatile("s_waitcnt lgkmcnt(0)" ::: "memory");
            if (L == 63) prog[w] = c;
        } else if (c == 15 && L == 63) {
            out_val = rb[30];  // step 510 = R[255][255]
        }
        asm volatile("" ::: "memory");
        if (w > 0 && L == 0) rdprog[w] = c;  // release writer's ring
    }

    if (w == 3 && L == 63) rout[p] = out_val * LN2;  // base-2 -> nats
}

// ---------------------------------------------------------------------------
// Kernel 3: loss = mean_b( r[b] - 0.5*(r[b+128] + r[b+256]) ) + 1e-5
// ---------------------------------------------------------------------------
__global__ void reduce_kernel(const float* __restrict__ rr, float* __restrict__ out) {
    const int t = threadIdx.x;  // 128 threads
    float v = rr[t] - 0.5f * (rr[t + 128] + rr[t + 256]);
#pragma unroll
    for (int o = 32; o > 0; o >>= 1) v += __shfl_down(v, o);
    __shared__ float sred[2];
    if ((t & 63) == 0) sred[t >> 6] = v;
    __syncthreads();
    if (t == 0) out[0] = (sred[0] + sred[1]) * (1.f / 128.f) + 1e-5f;
}

extern "C" void kernel_launch(void* const* d_in, const int* in_sizes, int n_in,
                              void* d_out, int out_size, void* d_ws, size_t ws_size,
                              hipStream_t stream) {
    const float* X = (const float*)d_in[0];  // outputs (128,256,64) f32
    const float* Y = (const float*)d_in[1];  // targets (128,256,64) f32
    float* out = (float*)d_out;

    const size_t dbytes = (size_t)NPAIR * NSEQ * NSEQ * sizeof(unsigned short);
    const size_t need = dbytes + (size_t)NPAIR * sizeof(float);
    if (ws_size < need) {
        hipMemsetAsync(d_out, 0x7f, sizeof(float), stream);  // sentinel
        return;
    }
    unsigned short* Sws = (unsigned short*)d_ws;
    float* rws = (float*)((char*)d_ws + dbytes);

    dist_kernel<<<NPAIR, 256, 0, stream>>>(X, Y, Sws);
    dtw_kernel<<<NPAIR, 256, 0, stream>>>(Sws, rws);
    reduce_kernel<<<1, 128, 0, stream>>>(rws, out);
}